// Round 1
// baseline (64.394 us; speedup 1.0000x reference)
//
#include <hip/hip_runtime.h>

// AdderVDSR collapses analytically:
//   adder_conv output = -sum|x-w| <= 0 strictly  =>  relu(...) == 0 exactly (fp32)
//   => all 16 residual layers produce exactly 0
//   => final out = pixel_shuffle(conv(x, w_up), 3)[o,Y,X] - C[o],
//      C[o] = sum_{c,kh,kw} |w_out[o,c,kh,kw]|   (uniform incl. borders, zero-pad)
//
// One kernel: block-reduce C[0..2] in LDS, then 1 thread per output pixel
// computes the 3 channels of the up-conv (27 MACs each) and subtracts C.

#define HW2 9216  // 96*96

__global__ __launch_bounds__(256) void adder_vdsr_collapsed(
    const float* __restrict__ x,      // [3][32][32]
    const float* __restrict__ w_up,   // [27][3][3][3]  (o = c_up*9 + ry*3 + rx)
    const float* __restrict__ w_out,  // [3][56][3][3] flat = 1512
    float* __restrict__ out)          // [3][96][96]
{
    __shared__ float Cs[3];
    __shared__ float wred[4][3];
    const int t = threadIdx.x;

    // ---- C[o] = sum of 504 |w_out| terms, o = 0..2 ----
    float p0 = 0.f, p1 = 0.f, p2 = 0.f;
    for (int i = t; i < 504; i += 256) {
        p0 += fabsf(w_out[i]);
        p1 += fabsf(w_out[504 + i]);
        p2 += fabsf(w_out[1008 + i]);
    }
    #pragma unroll
    for (int off = 32; off >= 1; off >>= 1) {
        p0 += __shfl_down(p0, off, 64);
        p1 += __shfl_down(p1, off, 64);
        p2 += __shfl_down(p2, off, 64);
    }
    if ((t & 63) == 0) {
        const int w = t >> 6;
        wred[w][0] = p0; wred[w][1] = p1; wred[w][2] = p2;
    }
    __syncthreads();
    if (t == 0) {
        Cs[0] = wred[0][0] + wred[1][0] + wred[2][0] + wred[3][0];
        Cs[1] = wred[0][1] + wred[1][1] + wred[2][1] + wred[3][1];
        Cs[2] = wred[0][2] + wred[1][2] + wred[2][2] + wred[3][2];
    }
    __syncthreads();

    // ---- up-conv + pixel_shuffle + bias ----
    const int idx = blockIdx.x * 256 + t;       // 0..9215
    const int Y  = idx / 96,  X  = idx - 96 * Y;
    const int y  = Y / 3,     ry = Y - 3 * y;
    const int x0 = X / 3,     rx = X - 3 * x0;
    const int osel = ry * 3 + rx;               // pixel-shuffle phase

    float acc0 = 0.f, acc1 = 0.f, acc2 = 0.f;
    #pragma unroll
    for (int kh = 0; kh < 3; ++kh) {
        const int yy = y + kh - 1;
        if (yy < 0 || yy >= 32) continue;
        #pragma unroll
        for (int kw = 0; kw < 3; ++kw) {
            const int xx = x0 + kw - 1;
            if (xx < 0 || xx >= 32) continue;
            #pragma unroll
            for (int ci = 0; ci < 3; ++ci) {
                const float xv = x[(ci * 32 + yy) * 32 + xx];
                // w_up[o][ci][kh][kw], o = oc*9 + osel
                acc0 += xv * w_up[(((0 * 9 + osel) * 3 + ci) * 3 + kh) * 3 + kw];
                acc1 += xv * w_up[(((1 * 9 + osel) * 3 + ci) * 3 + kh) * 3 + kw];
                acc2 += xv * w_up[(((2 * 9 + osel) * 3 + ci) * 3 + kh) * 3 + kw];
            }
        }
    }
    out[idx]            = acc0 - Cs[0];
    out[HW2 + idx]      = acc1 - Cs[1];
    out[2 * HW2 + idx]  = acc2 - Cs[2];
}

extern "C" void kernel_launch(void* const* d_in, const int* in_sizes, int n_in,
                              void* d_out, int out_size, void* d_ws, size_t ws_size,
                              hipStream_t stream) {
    const float* x     = (const float*)d_in[0];
    const float* w_up  = (const float*)d_in[1];
    // d_in[2] = w_in, d_in[3] = w_res — provably unused (their layers output exact zeros)
    const float* w_out = (const float*)d_in[4];
    float* out = (float*)d_out;

    adder_vdsr_collapsed<<<36, 256, 0, stream>>>(x, w_up, w_out, out);
}

// Round 2
// 64.242 us; speedup vs baseline: 1.0024x; 1.0024x over previous
//
#include <hip/hip_runtime.h>

// AdderVDSR collapses analytically (verified round 1, absmax 0.25 vs thr 0.865):
//   adder_conv output = -sum|x-w| <= 0  =>  relu(...) == 0 exactly (fp32)
//   => all 16 residual layers output exact zeros
//   => out = pixel_shuffle(conv(x, w_up), 3)[o,Y,X] - C[o],
//      C[o] = sum_{c,kh,kw} |w_out[o,c,kh,kw]|  (uniform incl. borders, zero-pad)
//
// Round 2: micro-tuned single kernel (float4 C-reduction, LDS-staged w_up).
// Measured dur_us is dominated by the harness's 256 MiB d_ws re-poison
// (~41 us fillBuffer @ 80% HBM peak per timed iter) — testing that floor.

#define HW2 9216  // 96*96

__global__ __launch_bounds__(256) void adder_vdsr_collapsed(
    const float* __restrict__ x,      // [3][32][32]
    const float* __restrict__ w_up,   // [27][3][3][3]  (o = c_up*9 + ry*3 + rx)
    const float* __restrict__ w_out,  // [3][56][3][3] flat = 1512 (= 378 float4)
    float* __restrict__ out)          // [3][96][96]
{
    __shared__ float Cs[3];
    __shared__ float wred[4][3];
    __shared__ float wup_s[729];
    const int t = threadIdx.x;

    // ---- stage w_up into LDS (729 floats) ----
    for (int i = t; i < 729; i += 256) wup_s[i] = w_up[i];

    // ---- C[o] = sum of 504 |w_out| terms, via float4 (126 per channel) ----
    const float4* __restrict__ w4 = (const float4*)w_out;
    float p0 = 0.f, p1 = 0.f, p2 = 0.f;
    if (t < 126) {
        float4 a = w4[t];
        float4 b = w4[126 + t];
        float4 c = w4[252 + t];
        p0 = fabsf(a.x) + fabsf(a.y) + fabsf(a.z) + fabsf(a.w);
        p1 = fabsf(b.x) + fabsf(b.y) + fabsf(b.z) + fabsf(b.w);
        p2 = fabsf(c.x) + fabsf(c.y) + fabsf(c.z) + fabsf(c.w);
    }
    #pragma unroll
    for (int off = 32; off >= 1; off >>= 1) {
        p0 += __shfl_down(p0, off, 64);
        p1 += __shfl_down(p1, off, 64);
        p2 += __shfl_down(p2, off, 64);
    }
    if ((t & 63) == 0) {
        const int w = t >> 6;
        wred[w][0] = p0; wred[w][1] = p1; wred[w][2] = p2;
    }
    __syncthreads();
    if (t == 0) {
        Cs[0] = wred[0][0] + wred[1][0];  // waves 2,3 had no t<126 lanes? (t<126 spans waves 0,1)
        Cs[1] = wred[0][1] + wred[1][1];
        Cs[2] = wred[0][2] + wred[1][2];
        // waves 2,3 contribute exact zeros; add anyway for clarity/safety:
        Cs[0] += wred[2][0] + wred[3][0];
        Cs[1] += wred[2][1] + wred[3][1];
        Cs[2] += wred[2][2] + wred[3][2];
    }
    __syncthreads();

    // ---- up-conv + pixel_shuffle + bias ----
    const int idx = blockIdx.x * 256 + t;       // 0..9215
    const int Y  = idx / 96,  X  = idx - 96 * Y;
    const int y  = Y / 3,     ry = Y - 3 * y;
    const int x0 = X / 3,     rx = X - 3 * x0;
    const int osel = ry * 3 + rx;               // pixel-shuffle phase

    float acc0 = 0.f, acc1 = 0.f, acc2 = 0.f;
    #pragma unroll
    for (int kh = 0; kh < 3; ++kh) {
        const int yy = y + kh - 1;
        if (yy < 0 || yy >= 32) continue;
        #pragma unroll
        for (int kw = 0; kw < 3; ++kw) {
            const int xx = x0 + kw - 1;
            if (xx < 0 || xx >= 32) continue;
            #pragma unroll
            for (int ci = 0; ci < 3; ++ci) {
                const float xv = x[(ci * 32 + yy) * 32 + xx];
                // wup_s[(o*3 + ci)*9 + kh*3 + kw], o = oc*9 + osel
                acc0 += xv * wup_s[((0 * 9 + osel) * 3 + ci) * 9 + kh * 3 + kw];
                acc1 += xv * wup_s[((1 * 9 + osel) * 3 + ci) * 9 + kh * 3 + kw];
                acc2 += xv * wup_s[((2 * 9 + osel) * 3 + ci) * 9 + kh * 3 + kw];
            }
        }
    }
    out[idx]            = acc0 - Cs[0];
    out[HW2 + idx]      = acc1 - Cs[1];
    out[2 * HW2 + idx]  = acc2 - Cs[2];
}

extern "C" void kernel_launch(void* const* d_in, const int* in_sizes, int n_in,
                              void* d_out, int out_size, void* d_ws, size_t ws_size,
                              hipStream_t stream) {
    const float* x     = (const float*)d_in[0];
    const float* w_up  = (const float*)d_in[1];
    // d_in[2] = w_in, d_in[3] = w_res — provably unused (their layers output exact zeros)
    const float* w_out = (const float*)d_in[4];
    float* out = (float*)d_out;

    adder_vdsr_collapsed<<<36, 256, 0, stream>>>(x, w_up, w_out, out);
}